// Round 1
// baseline (198.695 us; speedup 1.0000x reference)
//
#include <hip/hip_runtime.h>
#include <math.h>

// Problem constants (fixed by setup_inputs)
#define BB    8
#define DD    64
#define NPIX  32768
#define KK    19
#define PP    5
#define KP    (KK * PP)

// ---------------------------------------------------------------------------
// Kernel A: preprocess means/diagonal into per-component coefficients.
//   A[j][d]  = mu_n[j][d] * inv2[j][d]          (mu_n = l2-normalized means row)
//   Bc[j][d] = -0.5 * inv2[j][d]
//   cst[j]   = -0.5 * sum(mu_n^2 * inv2) - sum(log(scale)) - 0.5*D*log(2*pi)
// so that  logp_j(x) = cst[j] + sum_d x_d*A[j][d] + sum_d x_d^2*Bc[j][d]
// ---------------------------------------------------------------------------
__global__ void gmm_prep_kernel(const float* __restrict__ means,
                                const float* __restrict__ diag,
                                float* __restrict__ A,
                                float* __restrict__ Bc,
                                float* __restrict__ cst) {
    int j = blockIdx.x * blockDim.x + threadIdx.x;
    if (j >= KP) return;
    const float* mu = means + (size_t)j * DD;
    const float* sc = diag  + (size_t)j * DD;

    float ss = 0.f;
    for (int d = 0; d < DD; ++d) ss += mu[d] * mu[d];
    float nrm = sqrtf(ss);
    float inv = 1.f / fmaxf(nrm, 1e-12f);

    float c = 0.f, lg = 0.f;
    for (int d = 0; d < DD; ++d) {
        float mn = mu[d] * inv;
        float sd = sc[d];
        float i2 = 1.f / (sd * sd);
        A[(size_t)j * DD + d]  = mn * i2;
        Bc[(size_t)j * DD + d] = -0.5f * i2;
        c  += mn * mn * i2;
        lg += logf(sd);
    }
    // 0.5 * D * log(2*pi)
    const float half_d_log2pi = 0.5f * (float)DD * 1.8378770664093453f;
    cst[j] = -0.5f * c - lg - half_d_log2pi;
}

// ---------------------------------------------------------------------------
// Kernel B: one thread per pixel.
//   load x[0..63] (coalesced: lanes = consecutive pixels, stride NPIX per d)
//   layernorm(D) -> l2 normalize -> 95 component log-probs -> max over P
//   -> layernorm(K) -> 19 coalesced stores
// ---------------------------------------------------------------------------
__global__ __launch_bounds__(256) void gmm_main_kernel(
        const float* __restrict__ bf,      // [B, D, NPIX]
        const float* __restrict__ feat_w,  // [D]
        const float* __restrict__ feat_b,  // [D]
        const float* __restrict__ mask_w,  // [K]
        const float* __restrict__ mask_b,  // [K]
        const float* __restrict__ A,       // [KP, D]
        const float* __restrict__ Bc,      // [KP, D]
        const float* __restrict__ cst,     // [KP]
        float* __restrict__ out)           // [B, K, NPIX]
{
    int g = blockIdx.x * blockDim.x + threadIdx.x;
    if (g >= BB * NPIX) return;
    int b = g >> 15;            // NPIX = 2^15
    int n = g & (NPIX - 1);

    const float* xp = bf + (size_t)b * DD * NPIX + n;

    float x[DD];
    #pragma unroll
    for (int d = 0; d < DD; ++d) x[d] = xp[(size_t)d * NPIX];

    // --- layernorm over D ---
    float mu = 0.f;
    #pragma unroll
    for (int d = 0; d < DD; ++d) mu += x[d];
    mu *= (1.f / DD);
    float var = 0.f;
    #pragma unroll
    for (int d = 0; d < DD; ++d) { float t = x[d] - mu; var = fmaf(t, t, var); }
    var *= (1.f / DD);
    float r = rsqrtf(var + 1e-5f);
    #pragma unroll
    for (int d = 0; d < DD; ++d) x[d] = (x[d] - mu) * r * feat_w[d] + feat_b[d];

    // --- l2 normalize ---
    float s = 0.f;
    #pragma unroll
    for (int d = 0; d < DD; ++d) s = fmaf(x[d], x[d], s);
    float nn = sqrtf(s);
    float invn = 1.f / fmaxf(nn, 1e-12f);

    float xsq[DD];
    #pragma unroll
    for (int d = 0; d < DD; ++d) { x[d] *= invn; xsq[d] = x[d] * x[d]; }

    // --- 95 component log-probs, max over P per k ---
    float m[KK];
    for (int k = 0; k < KK; ++k) {
        float best = -3.4e38f;
        for (int p = 0; p < PP; ++p) {
            const int j = k * PP + p;
            const float* Aj = A  + (size_t)j * DD;
            const float* Bj = Bc + (size_t)j * DD;
            // 4 independent FMA chains to hide dependent-FMA latency
            float a0 = 0.f, a1 = 0.f, a2 = 0.f, a3 = 0.f;
            #pragma unroll
            for (int d = 0; d < DD; d += 2) {
                a0 = fmaf(x[d],       Aj[d],     a0);
                a1 = fmaf(xsq[d],     Bj[d],     a1);
                a2 = fmaf(x[d + 1],   Aj[d + 1], a2);
                a3 = fmaf(xsq[d + 1], Bj[d + 1], a3);
            }
            float acc = cst[j] + ((a0 + a1) + (a2 + a3));
            best = fmaxf(best, acc);
        }
        m[k] = best;
    }

    // --- layernorm over K (two-pass, matches reference) ---
    float mum = 0.f;
    #pragma unroll
    for (int k = 0; k < KK; ++k) mum += m[k];
    mum *= (1.f / KK);
    float varm = 0.f;
    #pragma unroll
    for (int k = 0; k < KK; ++k) { float t = m[k] - mum; varm = fmaf(t, t, varm); }
    varm *= (1.f / KK);
    float rm = rsqrtf(varm + 1e-5f);

    float* op = out + (size_t)b * KK * NPIX + n;
    #pragma unroll
    for (int k = 0; k < KK; ++k)
        op[(size_t)k * NPIX] = (m[k] - mum) * rm * mask_w[k] + mask_b[k];
}

extern "C" void kernel_launch(void* const* d_in, const int* in_sizes, int n_in,
                              void* d_out, int out_size, void* d_ws, size_t ws_size,
                              hipStream_t stream) {
    const float* base_feature = (const float*)d_in[0]; // [8, 64, 32768]
    const float* means        = (const float*)d_in[1]; // [19, 5, 64]
    const float* diagonal     = (const float*)d_in[2]; // [19, 5, 64]
    const float* feat_w       = (const float*)d_in[3]; // [64]
    const float* feat_b       = (const float*)d_in[4]; // [64]
    const float* mask_w       = (const float*)d_in[5]; // [19]
    const float* mask_b       = (const float*)d_in[6]; // [19]
    float* out = (float*)d_out;                        // [8, 19, 32768] fp32

    // Workspace layout (floats): A[KP*DD] | Bc[KP*DD] | cst[KP]  (~49 KB)
    float* A   = (float*)d_ws;
    float* Bc  = A  + KP * DD;
    float* cst = Bc + KP * DD;

    gmm_prep_kernel<<<(KP + 127) / 128, 128, 0, stream>>>(means, diagonal, A, Bc, cst);

    const int total = BB * NPIX;
    gmm_main_kernel<<<(total + 255) / 256, 256, 0, stream>>>(
        base_feature, feat_w, feat_b, mask_w, mask_b, A, Bc, cst, out);
}

// Round 2
// 198.602 us; speedup vs baseline: 1.0005x; 1.0005x over previous
//
#include <hip/hip_runtime.h>
#include <math.h>

// Problem constants (fixed by setup_inputs)
#define BB    8
#define DD    64
#define NPIX  32768
#define KK    19
#define PP    5
#define KP    (KK * PP)

// ---------------------------------------------------------------------------
// Kernel A: preprocess means/diagonal into per-component coefficients.
//   A[j][d]  = mu_n[j][d] * inv2[j][d]          (mu_n = l2-normalized means row)
//   Bc[j][d] = -0.5 * inv2[j][d]
//   cst[j]   = -0.5 * sum(mu_n^2 * inv2) - sum(log(scale)) - 0.5*D*log(2*pi)
// so that  logp_j(x) = cst[j] + sum_d x_d*A[j][d] + sum_d x_d^2*Bc[j][d]
// ---------------------------------------------------------------------------
__global__ void gmm_prep_kernel(const float* __restrict__ means,
                                const float* __restrict__ diag,
                                float* __restrict__ A,
                                float* __restrict__ Bc,
                                float* __restrict__ cst) {
    int j = blockIdx.x * blockDim.x + threadIdx.x;
    if (j >= KP) return;
    const float* mu = means + (size_t)j * DD;
    const float* sc = diag  + (size_t)j * DD;

    float ss = 0.f;
    for (int d = 0; d < DD; ++d) ss += mu[d] * mu[d];
    float nrm = sqrtf(ss);
    float inv = 1.f / fmaxf(nrm, 1e-12f);

    float c = 0.f, lg = 0.f;
    for (int d = 0; d < DD; ++d) {
        float mn = mu[d] * inv;
        float sd = sc[d];
        float i2 = 1.f / (sd * sd);
        A[(size_t)j * DD + d]  = mn * i2;
        Bc[(size_t)j * DD + d] = -0.5f * i2;
        c  += mn * mn * i2;
        lg += logf(sd);
    }
    // 0.5 * D * log(2*pi)
    const float half_d_log2pi = 0.5f * (float)DD * 1.8378770664093453f;
    cst[j] = -0.5f * c - lg - half_d_log2pi;
}

// ---------------------------------------------------------------------------
// Kernel B: one thread per pixel.
// __launch_bounds__(256, 2): min 2 waves/EU -> VGPR cap 256, so x[64]+xsq[64]
// stay register-resident (round 1's (256) default capped VGPRs at 64 and the
// compiler re-loaded x from cache 95x per pixel -> L2-bandwidth-bound).
// ---------------------------------------------------------------------------
__global__ __launch_bounds__(256, 2) void gmm_main_kernel(
        const float* __restrict__ bf,      // [B, D, NPIX]
        const float* __restrict__ feat_w,  // [D]
        const float* __restrict__ feat_b,  // [D]
        const float* __restrict__ mask_w,  // [K]
        const float* __restrict__ mask_b,  // [K]
        const float* __restrict__ A,       // [KP, D]
        const float* __restrict__ Bc,      // [KP, D]
        const float* __restrict__ cst,     // [KP]
        float* __restrict__ out)           // [B, K, NPIX]
{
    int g = blockIdx.x * blockDim.x + threadIdx.x;
    if (g >= BB * NPIX) return;
    int b = g >> 15;            // NPIX = 2^15
    int n = g & (NPIX - 1);

    const float* xp = bf + (size_t)b * DD * NPIX + n;

    float x[DD];
    #pragma unroll
    for (int d = 0; d < DD; ++d) x[d] = xp[(size_t)d * NPIX];

    // --- layernorm over D ---
    float mu = 0.f;
    #pragma unroll
    for (int d = 0; d < DD; ++d) mu += x[d];
    mu *= (1.f / DD);
    float var = 0.f;
    #pragma unroll
    for (int d = 0; d < DD; ++d) { float t = x[d] - mu; var = fmaf(t, t, var); }
    var *= (1.f / DD);
    float r = rsqrtf(var + 1e-5f);
    #pragma unroll
    for (int d = 0; d < DD; ++d) x[d] = (x[d] - mu) * r * feat_w[d] + feat_b[d];

    // --- l2 normalize ---
    float s = 0.f;
    #pragma unroll
    for (int d = 0; d < DD; ++d) s = fmaf(x[d], x[d], s);
    float nn = sqrtf(s);
    float invn = 1.f / fmaxf(nn, 1e-12f);

    float xsq[DD];
    #pragma unroll
    for (int d = 0; d < DD; ++d) { x[d] *= invn; xsq[d] = x[d] * x[d]; }

    // --- 95 component log-probs, max over P per k ---
    float m[KK];
    for (int k = 0; k < KK; ++k) {
        float best = -3.4e38f;
        for (int p = 0; p < PP; ++p) {
            const int j = k * PP + p;
            const float* Aj = A  + (size_t)j * DD;
            const float* Bj = Bc + (size_t)j * DD;
            // 4 independent FMA chains to hide dependent-FMA latency
            float a0 = 0.f, a1 = 0.f, a2 = 0.f, a3 = 0.f;
            #pragma unroll
            for (int d = 0; d < DD; d += 2) {
                a0 = fmaf(x[d],       Aj[d],     a0);
                a1 = fmaf(xsq[d],     Bj[d],     a1);
                a2 = fmaf(x[d + 1],   Aj[d + 1], a2);
                a3 = fmaf(xsq[d + 1], Bj[d + 1], a3);
            }
            float acc = cst[j] + ((a0 + a1) + (a2 + a3));
            best = fmaxf(best, acc);
        }
        m[k] = best;
    }

    // --- layernorm over K (two-pass, matches reference) ---
    float mum = 0.f;
    #pragma unroll
    for (int k = 0; k < KK; ++k) mum += m[k];
    mum *= (1.f / KK);
    float varm = 0.f;
    #pragma unroll
    for (int k = 0; k < KK; ++k) { float t = m[k] - mum; varm = fmaf(t, t, varm); }
    varm *= (1.f / KK);
    float rm = rsqrtf(varm + 1e-5f);

    float* op = out + (size_t)b * KK * NPIX + n;
    #pragma unroll
    for (int k = 0; k < KK; ++k)
        op[(size_t)k * NPIX] = (m[k] - mum) * rm * mask_w[k] + mask_b[k];
}

extern "C" void kernel_launch(void* const* d_in, const int* in_sizes, int n_in,
                              void* d_out, int out_size, void* d_ws, size_t ws_size,
                              hipStream_t stream) {
    const float* base_feature = (const float*)d_in[0]; // [8, 64, 32768]
    const float* means        = (const float*)d_in[1]; // [19, 5, 64]
    const float* diagonal     = (const float*)d_in[2]; // [19, 5, 64]
    const float* feat_w       = (const float*)d_in[3]; // [64]
    const float* feat_b       = (const float*)d_in[4]; // [64]
    const float* mask_w       = (const float*)d_in[5]; // [19]
    const float* mask_b       = (const float*)d_in[6]; // [19]
    float* out = (float*)d_out;                        // [8, 19, 32768] fp32

    // Workspace layout (floats): A[KP*DD] | Bc[KP*DD] | cst[KP]  (~49 KB)
    float* A   = (float*)d_ws;
    float* Bc  = A  + KP * DD;
    float* cst = Bc + KP * DD;

    gmm_prep_kernel<<<(KP + 127) / 128, 128, 0, stream>>>(means, diagonal, A, Bc, cst);

    const int total = BB * NPIX;
    gmm_main_kernel<<<(total + 255) / 256, 256, 0, stream>>>(
        base_feature, feat_w, feat_b, mask_w, mask_b, A, Bc, cst, out);
}

// Round 3
// 147.051 us; speedup vs baseline: 1.3512x; 1.3506x over previous
//
#include <hip/hip_runtime.h>
#include <math.h>

// Problem constants (fixed by setup_inputs)
#define BB    8
#define DD    64
#define NPIX  32768
#define KK    19
#define PP    5
#define KP    95      // 19*5
#define KPAD  96      // padded comps (j=95 row zeroed)

typedef _Float16 half8 __attribute__((ext_vector_type(8)));
typedef float f32x4 __attribute__((ext_vector_type(4)));

// LDS geometry for the main kernel
#define ROW_B   528            // u-tile row stride bytes: 256(uh)+256(ul)+16 pad, 16B aligned
#define SLOT_B  8448           // 16 rows * ROW_B: one px-tile's u region == one logp slot
#define UT_B    33792          // 64 rows * ROW_B
#define SCR_OFF 33792          // phase-A partial sums: f32 [2][5][64] = 2560 B
#define LDS_B   36352

// ---------------------------------------------------------------------------
// Prep: bake coefficients.
//   k-interleaved: C[j][2d] = mu_n*inv2 (x-term), C[j][2d+1] = -0.5*inv2 (x^2-term)
//   split fp16: Ch = f16(C), Cl = f16(C - Ch)
//   cst[j] = -0.5*sum(mu_n^2*inv2) - sum(log(scale)) - 32*log(2*pi)
//   block 95: zero row 95, and scal = {sum(w^2), sum(w*b), sum(b^2)}
// ---------------------------------------------------------------------------
__global__ __launch_bounds__(64) void gmm_prep(
        const float* __restrict__ means, const float* __restrict__ diag,
        const float* __restrict__ feat_w, const float* __restrict__ feat_b,
        _Float16* __restrict__ Ch, _Float16* __restrict__ Cl,
        float* __restrict__ cst, float* __restrict__ scal) {
    int j = blockIdx.x;
    int d = threadIdx.x;
    if (j < KP) {
        float mu = means[j * DD + d];
        float sc = diag[j * DD + d];
        float ss = mu * mu;
        #pragma unroll
        for (int off = 32; off; off >>= 1) ss += __shfl_xor(ss, off);
        float inv = 1.f / fmaxf(sqrtf(ss), 1e-12f);
        float mn = mu * inv;
        float i2 = 1.f / (sc * sc);
        float A = mn * i2;
        float B = -0.5f * i2;
        _Float16 ah = (_Float16)A; _Float16 al = (_Float16)(A - (float)ah);
        _Float16 bh = (_Float16)B; _Float16 bl = (_Float16)(B - (float)bh);
        Ch[j * 128 + 2 * d]     = ah;
        Ch[j * 128 + 2 * d + 1] = bh;
        Cl[j * 128 + 2 * d]     = al;
        Cl[j * 128 + 2 * d + 1] = bl;
        float c1 = mn * mn * i2;
        float c2 = logf(sc);
        #pragma unroll
        for (int off = 32; off; off >>= 1) {
            c1 += __shfl_xor(c1, off);
            c2 += __shfl_xor(c2, off);
        }
        if (d == 0) cst[j] = -0.5f * c1 - c2 - 58.8120661251f; // 32*ln(2*pi)
    } else {
        // j == 95: zero pad row; compute feature-LN scalars
        Ch[95 * 128 + 2 * d] = (_Float16)0.f; Ch[95 * 128 + 2 * d + 1] = (_Float16)0.f;
        Cl[95 * 128 + 2 * d] = (_Float16)0.f; Cl[95 * 128 + 2 * d + 1] = (_Float16)0.f;
        float w = feat_w[d], b = feat_b[d];
        float s0 = w * w, s1 = w * b, s2 = b * b;
        #pragma unroll
        for (int off = 32; off; off >>= 1) {
            s0 += __shfl_xor(s0, off);
            s1 += __shfl_xor(s1, off);
            s2 += __shfl_xor(s2, off);
        }
        if (d == 0) { cst[95] = 0.f; scal[0] = s0; scal[1] = s1; scal[2] = s2; }
    }
}

// ---------------------------------------------------------------------------
// Main: 2 waves / 64 pixels per block.
//   A: coalesced x loads (x kept in 32 regs/lane), one-pass moments -> alpha,e,f
//   B: u_d = alpha*w_d*x_d + e*b_d + f*w_d ; split fp16 hi/lo -> LDS u-tile
//   MFMA: wave w owns j-tiles {3w,3w+1,3w+2}; coeff frags persistent in VGPRs;
//         logp written into LDS slots aliased over the just-consumed u rows
//   Epilogue: thread=pixel: max over P, layernorm over K, coalesced stores
// ---------------------------------------------------------------------------
__global__ __launch_bounds__(128, 2) void gmm_main(
        const float* __restrict__ bf,
        const float* __restrict__ feat_w, const float* __restrict__ feat_b,
        const float* __restrict__ mask_w, const float* __restrict__ mask_b,
        const _Float16* __restrict__ Ch, const _Float16* __restrict__ Cl,
        const float* __restrict__ cst, const float* __restrict__ scal,
        float* __restrict__ out) {
    __shared__ __align__(16) unsigned char smem[LDS_B];
    float* scratch = (float*)(smem + SCR_OFF);  // [2][5][64]

    const int tid  = threadIdx.x;
    const int w    = tid >> 6;
    const int lane = tid & 63;
    const int m15  = lane & 15;
    const int q    = lane >> 4;
    const int bidx = blockIdx.x;
    const int b    = bidx >> 9;          // 512 blocks per batch image
    const int n0   = (bidx & 511) << 6;  // 64 px per block

    // ---- persistent coefficient fragments (issued early; L2-resident) ----
    half8 Ahf[3][4], Alf[3][4];
    #pragma unroll
    for (int t = 0; t < 3; ++t) {
        const int row = (3 * w + t) * 16 + m15;
        #pragma unroll
        for (int ks = 0; ks < 4; ++ks) {
            Ahf[t][ks] = *(const half8*)(Ch + row * 128 + ks * 32 + q * 8);
            Alf[t][ks] = *(const half8*)(Cl + row * 128 + ks * 32 + q * 8);
        }
    }

    // ---- phase A: moments (wave w covers d in [32w, 32w+32), lane = pixel) ----
    const int dbase = w * 32;
    const float* xp = bf + (size_t)b * (DD * NPIX) + (size_t)dbase * NPIX + n0 + lane;
    float xs[32];
    #pragma unroll
    for (int i = 0; i < 32; ++i) xs[i] = xp[(size_t)i * NPIX];

    float S1 = 0.f, S2 = 0.f, S3 = 0.f, S4 = 0.f, S5 = 0.f;
    #pragma unroll
    for (int i = 0; i < 32; ++i) {
        float wd = feat_w[dbase + i];
        float bd = feat_b[dbase + i];
        float x  = xs[i];
        float t  = wd * x;
        S1 += x;
        S2 = fmaf(x, x, S2);
        S3 = fmaf(t, t, S3);
        S4 = fmaf(t, wd, S4);
        S5 = fmaf(t, bd, S5);
    }
    scratch[w * 320 +   0 + lane] = S1;
    scratch[w * 320 +  64 + lane] = S2;
    scratch[w * 320 + 128 + lane] = S3;
    scratch[w * 320 + 192 + lane] = S4;
    scratch[w * 320 + 256 + lane] = S5;
    __syncthreads();
    {
        const int ow = (1 - w) * 320;
        S1 += scratch[ow +   0 + lane];
        S2 += scratch[ow +  64 + lane];
        S3 += scratch[ow + 128 + lane];
        S4 += scratch[ow + 192 + lane];
        S5 += scratch[ow + 256 + lane];
    }
    const float W2 = scal[0], WB = scal[1], B2 = scal[2];
    float mu  = S1 * (1.f / 64.f);
    float var = fmaxf(S2 * (1.f / 64.f) - mu * mu, 0.f);
    float r   = rsqrtf(var + 1e-5f);
    float Sy2 = r * r * (S3 - 2.f * mu * S4 + mu * mu * W2)
              + 2.f * r * (S5 - mu * WB) + B2;
    float nrm  = sqrtf(fmaxf(Sy2, 0.f));
    float invn = 1.f / fmaxf(nrm, 1e-12f);
    float alpha = invn * r;
    float e = invn;
    float f = -alpha * mu;

    // ---- phase B: build split-fp16 u-tile in LDS (lane = pixel row) ----
    {
        unsigned char* rowp = smem + lane * ROW_B;
        #pragma unroll
        for (int g = 0; g < 8; ++g) {
            half8 vh, vl;
            #pragma unroll
            for (int jj = 0; jj < 4; ++jj) {
                int d = dbase + 4 * g + jj;
                float wd = feat_w[d];
                float bd = feat_b[d];
                float c  = fmaf(f, wd, e * bd);
                float u  = fmaf(alpha * wd, xs[4 * g + jj], c);
                float us = u * u;
                _Float16 uh = (_Float16)u;  _Float16 ul = (_Float16)(u  - (float)uh);
                _Float16 qh = (_Float16)us; _Float16 ql = (_Float16)(us - (float)qh);
                vh[2 * jj] = uh; vh[2 * jj + 1] = qh;
                vl[2 * jj] = ul; vl[2 * jj + 1] = ql;
            }
            *(half8*)(rowp + 4 * (dbase + 4 * g))       = vh;  // k=2d  -> byte 4d
            *(half8*)(rowp + 256 + 4 * (dbase + 4 * g)) = vl;
        }
    }
    __syncthreads();  // u-tile ready

    // ---- MFMA phase: 4 px-tiles of 16; 36 MFMAs per tile per wave ----
    #pragma unroll 1
    for (int s = 0; s < 4; ++s) {
        const unsigned ubase = (unsigned)(s * 16 + m15) * ROW_B + q * 16;
        half8 Uh[4], Ul[4];
        #pragma unroll
        for (int ks = 0; ks < 4; ++ks) {
            Uh[ks] = *(const half8*)(smem + ubase + ks * 64);
            Ul[ks] = *(const half8*)(smem + ubase + 256 + ks * 64);
        }
        __syncthreads();  // all reads of u[s] done before logp[s] overwrites it

        f32x4 a0 = {0.f, 0.f, 0.f, 0.f}, a1 = a0, a2 = a0;
        #pragma unroll
        for (int ks = 0; ks < 4; ++ks) {
            a0 = __builtin_amdgcn_mfma_f32_16x16x32_f16(Ahf[0][ks], Uh[ks], a0, 0, 0, 0);
            a1 = __builtin_amdgcn_mfma_f32_16x16x32_f16(Ahf[1][ks], Uh[ks], a1, 0, 0, 0);
            a2 = __builtin_amdgcn_mfma_f32_16x16x32_f16(Ahf[2][ks], Uh[ks], a2, 0, 0, 0);
        }
        #pragma unroll
        for (int ks = 0; ks < 4; ++ks) {
            a0 = __builtin_amdgcn_mfma_f32_16x16x32_f16(Ahf[0][ks], Ul[ks], a0, 0, 0, 0);
            a1 = __builtin_amdgcn_mfma_f32_16x16x32_f16(Ahf[1][ks], Ul[ks], a1, 0, 0, 0);
            a2 = __builtin_amdgcn_mfma_f32_16x16x32_f16(Ahf[2][ks], Ul[ks], a2, 0, 0, 0);
        }
        #pragma unroll
        for (int ks = 0; ks < 4; ++ks) {
            a0 = __builtin_amdgcn_mfma_f32_16x16x32_f16(Alf[0][ks], Uh[ks], a0, 0, 0, 0);
            a1 = __builtin_amdgcn_mfma_f32_16x16x32_f16(Alf[1][ks], Uh[ks], a1, 0, 0, 0);
            a2 = __builtin_amdgcn_mfma_f32_16x16x32_f16(Alf[2][ks], Uh[ks], a2, 0, 0, 0);
        }

        // write logp slot s (aliased over u rows [16s,16s+16)); stride 17 f32, +64B/slot skew
        unsigned char* slotp = smem + s * SLOT_B + s * 64;
        #pragma unroll
        for (int rg = 0; rg < 4; ++rg) {
            int j0 = (3 * w + 0) * 16 + q * 4 + rg;
            int j1 = (3 * w + 1) * 16 + q * 4 + rg;
            int j2 = (3 * w + 2) * 16 + q * 4 + rg;
            *(float*)(slotp + (j0 * 17 + m15) * 4) = a0[rg];
            *(float*)(slotp + (j1 * 17 + m15) * 4) = a1[rg];
            *(float*)(slotp + (j2 * 17 + m15) * 4) = a2[rg];
        }
    }
    __syncthreads();

    // ---- epilogue: lanes 0..31 of each wave -> one pixel each ----
    if ((lane & 32) == 0) {
        int px   = w * 32 + (lane & 31);
        int slot = px >> 4;
        int col  = px & 15;
        const unsigned char* sb = smem + slot * SLOT_B + slot * 64;
        float m[KK];
        #pragma unroll
        for (int k = 0; k < KK; ++k) {
            float best = -3.4e38f;
            #pragma unroll
            for (int p = 0; p < PP; ++p) {
                int j = 5 * k + p;
                float v = *(const float*)(sb + (j * 17 + col) * 4) + cst[j];
                best = fmaxf(best, v);
            }
            m[k] = best;
        }
        float mum = 0.f;
        #pragma unroll
        for (int k = 0; k < KK; ++k) mum += m[k];
        mum *= (1.f / 19.f);
        float varm = 0.f;
        #pragma unroll
        for (int k = 0; k < KK; ++k) { float t = m[k] - mum; varm = fmaf(t, t, varm); }
        varm *= (1.f / 19.f);
        float rm = rsqrtf(varm + 1e-5f);
        float* op = out + (size_t)b * (KK * NPIX) + n0 + px;
        #pragma unroll
        for (int k = 0; k < KK; ++k)
            op[(size_t)k * NPIX] = (m[k] - mum) * rm * mask_w[k] + mask_b[k];
    }
}

extern "C" void kernel_launch(void* const* d_in, const int* in_sizes, int n_in,
                              void* d_out, int out_size, void* d_ws, size_t ws_size,
                              hipStream_t stream) {
    const float* base_feature = (const float*)d_in[0]; // [8, 64, 32768]
    const float* means        = (const float*)d_in[1]; // [19, 5, 64]
    const float* diagonal     = (const float*)d_in[2]; // [19, 5, 64]
    const float* feat_w       = (const float*)d_in[3]; // [64]
    const float* feat_b       = (const float*)d_in[4]; // [64]
    const float* mask_w       = (const float*)d_in[5]; // [19]
    const float* mask_b       = (const float*)d_in[6]; // [19]
    float* out = (float*)d_out;                        // [8, 19, 32768] fp32

    // ws layout: Ch[96*128] f16 | Cl[96*128] f16 | cst[96] f32 | scal[3] f32
    _Float16* Ch = (_Float16*)d_ws;
    _Float16* Cl = Ch + KPAD * 128;
    float* cst   = (float*)(Cl + KPAD * 128);
    float* scal  = cst + KPAD;

    gmm_prep<<<KPAD, 64, 0, stream>>>(means, diagonal, feat_w, feat_b, Ch, Cl, cst, scal);

    gmm_main<<<(BB * NPIX) / 64, 128, 0, stream>>>(
        base_feature, feat_w, feat_b, mask_w, mask_b, Ch, Cl, cst, scal, out);
}